// Round 8
// baseline (294.724 us; speedup 1.0000x reference)
//
#include <hip/hip_runtime.h>
#include <hip/hip_bf16.h>
#include <math.h>

// Problem constants: S=4, B=1, C=128, h=w=d=10 -> N=1000, L=4000, nL=2, H=8, Dh=16
#define LL 4000
#define CC 128
#define NN 1000
#define NLAYER 2
#define KSPLIT 4                        // == S; split-K aligned to sequences
#define SCLOG2 0.36067376022224085f    // 0.25 * log2(e), folded into Q
#define KROW 18                        // padded LDS row (shorts) for K tile [32][KROW]
#define VROW 34                        // padded LDS row (shorts) for V^T tile [16][VROW]

typedef __attribute__((ext_vector_type(4))) short bf16x4;
typedef __attribute__((ext_vector_type(8))) short short8;
typedef __attribute__((ext_vector_type(4))) float f32x4;
typedef __attribute__((ext_vector_type(2))) unsigned int u32x2;

__device__ __forceinline__ short bf16rne(float f) {
    return __builtin_bit_cast(short, __float2bfloat16(f));
}

// pack 4 f32 -> 4 bf16 (truncate) via 2x v_perm_b32
__device__ __forceinline__ bf16x4 pack4(const float* p) {
    unsigned w01 = __builtin_amdgcn_perm(__builtin_bit_cast(unsigned, p[1]),
                                         __builtin_bit_cast(unsigned, p[0]),
                                         0x07060302u);
    unsigned w23 = __builtin_amdgcn_perm(__builtin_bit_cast(unsigned, p[3]),
                                         __builtin_bit_cast(unsigned, p[2]),
                                         0x07060302u);
    u32x2 w = {w01, w23};
    return __builtin_bit_cast(bf16x4, w);
}

// ---------------------------------------------------------------------------
// tokenize: z[S,1,C,N] + seq_embed[S,C] -> tok[L,C] (f32) + tokb (bf16)
__global__ void tokenize_kernel(const float* __restrict__ z,
                                const float* __restrict__ se,
                                float* __restrict__ tok,
                                short* __restrict__ tokb) {
    int idx = blockIdx.x * blockDim.x + threadIdx.x;
    if (idx >= LL * CC) return;
    int c = idx & (CC - 1);
    int t = idx >> 7;
    int s = t / NN;
    int n = t - s * NN;
    float v = z[(s * CC + c) * NN + n] + se[s * CC + c];
    tok[idx] = v;
    tokb[idx] = bf16rne(v);
}

// detokenize: tok[L,C] -> out[(s*C+c)*N + n]
__global__ void detok_kernel(const float* __restrict__ tok,
                             float* __restrict__ out) {
    int idx = blockIdx.x * blockDim.x + threadIdx.x;
    if (idx >= LL * CC) return;
    int n = idx % NN;
    int sc = idx / NN;
    int c = sc & (CC - 1);
    int s = sc >> 7;
    out[idx] = tok[(s * NN + n) * CC + c];
}

// kbw[l*KSPLIT+z] = r[z]^beta[l]  (per-sequence softmax weight; row term of
// log R is softmax-invariant, clamp inactive since r>=0.1)
__global__ void kbw_kernel(const float* __restrict__ r,
                           const float* __restrict__ beta,
                           float* __restrict__ kbw) {
    int idx = threadIdx.x;
    if (idx >= NLAYER * KSPLIT) return;
    int l = idx / KSPLIT;
    int z = idx - l * KSPLIT;
    kbw[idx] = exp2f(beta[l] * __log2f(r[z]));
}

// ---------------------------------------------------------------------------
// weight prep: bf16 + transpose -> Wt[N][K]
__global__ void prep_weights(const float* __restrict__ Wq, const float* __restrict__ Wk,
                             const float* __restrict__ Wv, const float* __restrict__ Wp,
                             const float* __restrict__ w1, const float* __restrict__ w2,
                             short* __restrict__ wt8, short* __restrict__ w1t,
                             short* __restrict__ w2t) {
    int idx = blockIdx.x * blockDim.x + threadIdx.x;
    if (idx < 8 * 16384) {
        int m = idx >> 14, i = idx & 16383;
        int n = i >> 7, k = i & 127;
        const float* src = (m < 2) ? Wq + (size_t)m * 16384
                         : (m < 4) ? Wk + (size_t)(m - 2) * 16384
                         : (m < 6) ? Wv + (size_t)(m - 4) * 16384
                                   : Wp + (size_t)(m - 6) * 16384;
        wt8[idx] = bf16rne(src[k * 128 + n]);
    } else if (idx < 8 * 16384 + 65536) {
        int i = idx - 8 * 16384;
        int n = i >> 7, k = i & 127;
        w1t[i] = bf16rne(w1[(size_t)k * 512 + n]);
    } else if (idx < 8 * 16384 + 2 * 65536) {
        int i = idx - 8 * 16384 - 65536;
        int n = i >> 9, k = i & 511;
        w2t[i] = bf16rne(w2[(size_t)k * 128 + n]);
    }
}

// ---------------------------------------------------------------------------
// MFMA GEMM body: out[M,N] = act(A[M,K] @ Wt[N,K]^T + bias)
// flags: 1 = bf16 out, 2 = exact GELU, 4 = bf16 transposed out [N][M],
//        8 = *SCLOG2, 16 = bf16 head-major out [N/16][M][16]
__device__ __forceinline__ void gemm_body(
        const short* __restrict__ A, const short* __restrict__ Wt,
        const float* __restrict__ bias, void* __restrict__ outp,
        int M, int K, int N, int flags, int row0, int col0) {
    __shared__ short Al[16][136];
    __shared__ short Wl[128][136];
    const int tid = threadIdx.x;
    const int lane = tid & 63;
    const int w = tid >> 6;
    const int lq = lane & 15, g = lane >> 4;

    f32x4 acc[2] = {{0.f,0.f,0.f,0.f},{0.f,0.f,0.f,0.f}};

    for (int kc = 0; kc < K; kc += 128) {
        {
            int r = tid >> 4, c = (tid & 15) * 8;
            *(short8*)&Al[r][c] = *(const short8*)(A + (size_t)(row0 + r) * K + kc + c);
        }
        {
            int c = (tid & 15) * 8;
            int nb = tid >> 4;
            #pragma unroll
            for (int i = 0; i < 8; ++i) {
                int n = nb + i * 16;
                *(short8*)&Wl[n][c] = *(const short8*)(Wt + (size_t)(col0 + n) * K + kc + c);
            }
        }
        __syncthreads();
        bf16x4 af[8];
        #pragma unroll
        for (int ks = 0; ks < 8; ++ks)
            af[ks] = *(const bf16x4*)&Al[lq][ks * 16 + g * 4];
        #pragma unroll
        for (int ct = 0; ct < 2; ++ct) {
            int n = (w * 2 + ct) * 16 + lq;
            #pragma unroll
            for (int ks = 0; ks < 8; ++ks) {
                bf16x4 bfr = *(const bf16x4*)&Wl[n][ks * 16 + g * 4];
                acc[ct] = __builtin_amdgcn_mfma_f32_16x16x16bf16_1k(af[ks], bfr, acc[ct], 0, 0, 0);
            }
        }
        __syncthreads();
    }
    #pragma unroll
    for (int ct = 0; ct < 2; ++ct) {
        int col = col0 + (w * 2 + ct) * 16 + lq;
        float bv = bias ? bias[col] : 0.f;
        float v[4];
        #pragma unroll
        for (int r = 0; r < 4; ++r) {
            v[r] = acc[ct][r] + bv;
            if (flags & 2) v[r] = 0.5f * v[r] * (1.f + erff(v[r] * 0.70710678118654752f));
            if (flags & 8) v[r] *= SCLOG2;
        }
        if (flags & 4) {
            bf16x4 res = {bf16rne(v[0]), bf16rne(v[1]), bf16rne(v[2]), bf16rne(v[3])};
            *(bf16x4*)((short*)outp + (size_t)col * M + row0 + g * 4) = res;
        } else if (flags & 16) {   // head-major [H][M][16]
            #pragma unroll
            for (int r = 0; r < 4; ++r)
                ((short*)outp)[((size_t)(col >> 4) * M + (row0 + g * 4 + r)) * 16 + (col & 15)] = bf16rne(v[r]);
        } else if (flags & 1) {
            #pragma unroll
            for (int r = 0; r < 4; ++r)
                ((short*)outp)[(size_t)(row0 + g * 4 + r) * N + col] = bf16rne(v[r]);
        } else {
            #pragma unroll
            for (int r = 0; r < 4; ++r)
                ((float*)outp)[(size_t)(row0 + g * 4 + r) * N + col] = v[r];
        }
    }
}

__global__ __launch_bounds__(256) void mfma_gemm(
        const short* __restrict__ A, const short* __restrict__ Wt,
        const float* __restrict__ bias, void* __restrict__ outp,
        int M, int K, int N, int flags) {
    gemm_body(A, Wt, bias, outp, M, K, N, flags,
              blockIdx.x * 16, blockIdx.y * 128);
}

// fused QKV: z=0 Q (bf16, *SCLOG2), z=1 K (head-major [H][L][16]), z=2 V^T [C][L]
__global__ __launch_bounds__(256) void mfma_gemm3(
        const short* __restrict__ A,
        const short* __restrict__ W0, const short* __restrict__ W1,
        const short* __restrict__ W2,
        short* __restrict__ o0, short* __restrict__ o1, short* __restrict__ o2,
        int M, int K, int N) {
    const short* Wt = (blockIdx.z == 0) ? W0 : (blockIdx.z == 1) ? W1 : W2;
    short* o = (blockIdx.z == 0) ? o0 : (blockIdx.z == 1) ? o1 : o2;
    int flags = (blockIdx.z == 0) ? (1 | 8) : (blockIdx.z == 1) ? 16 : 4;
    gemm_body(A, Wt, nullptr, o, M, K, N, flags, blockIdx.x * 16, 0);
}

// ---------------------------------------------------------------------------
// Fused MFMA GEMM (N=128) + residual add + LayerNorm. Block = 4 waves =
// 16 full rows; stats via intra-wave shuffles + tiny LDS exchange.
// Writes f32 (next residual) + bf16 (next GEMM input).
__global__ __launch_bounds__(256) void mfma_gemm_ln(
        const short* __restrict__ A, const short* __restrict__ Wt,
        const float* __restrict__ bias, const float* __restrict__ resid,
        const float* __restrict__ gam, const float* __restrict__ bet,
        float* __restrict__ outf, short* __restrict__ outb,
        int M, int K) {
    __shared__ short Al[16][136];
    __shared__ short Wl[128][136];
    __shared__ float sL[4][4][4], s2L[4][4][4];
    const int tid = threadIdx.x;
    const int lane = tid & 63;
    const int w = tid >> 6;
    const int lq = lane & 15, g = lane >> 4;
    const int row0 = blockIdx.x * 16;

    f32x4 acc[2] = {{0.f,0.f,0.f,0.f},{0.f,0.f,0.f,0.f}};

    for (int kc = 0; kc < K; kc += 128) {
        {
            int r = tid >> 4, c = (tid & 15) * 8;
            *(short8*)&Al[r][c] = *(const short8*)(A + (size_t)(row0 + r) * K + kc + c);
        }
        {
            int c = (tid & 15) * 8;
            int nb = tid >> 4;
            #pragma unroll
            for (int i = 0; i < 8; ++i) {
                int n = nb + i * 16;
                *(short8*)&Wl[n][c] = *(const short8*)(Wt + (size_t)n * K + kc + c);
            }
        }
        __syncthreads();
        bf16x4 af[8];
        #pragma unroll
        for (int ks = 0; ks < 8; ++ks)
            af[ks] = *(const bf16x4*)&Al[lq][ks * 16 + g * 4];
        #pragma unroll
        for (int ct = 0; ct < 2; ++ct) {
            int n = (w * 2 + ct) * 16 + lq;
            #pragma unroll
            for (int ks = 0; ks < 8; ++ks) {
                bf16x4 bfr = *(const bf16x4*)&Wl[n][ks * 16 + g * 4];
                acc[ct] = __builtin_amdgcn_mfma_f32_16x16x16bf16_1k(af[ks], bfr, acc[ct], 0, 0, 0);
            }
        }
        __syncthreads();
    }

    // epilogue: v = acc + bias + residual, then block-wide LN over 128 cols
    float v[2][4];
    int cols[2] = {(w * 2) * 16 + lq, (w * 2 + 1) * 16 + lq};
    #pragma unroll
    for (int ct = 0; ct < 2; ++ct) {
        float bv = bias ? bias[cols[ct]] : 0.f;
        #pragma unroll
        for (int r = 0; r < 4; ++r)
            v[ct][r] = acc[ct][r] + bv +
                       resid[(size_t)(row0 + g * 4 + r) * CC + cols[ct]];
    }
    float sr[4], s2r[4];
    #pragma unroll
    for (int r = 0; r < 4; ++r) {
        sr[r]  = v[0][r] + v[1][r];
        s2r[r] = v[0][r] * v[0][r] + v[1][r] * v[1][r];
    }
    #pragma unroll
    for (int off = 1; off < 16; off <<= 1) {
        #pragma unroll
        for (int r = 0; r < 4; ++r) {
            sr[r]  += __shfl_xor(sr[r],  off);
            s2r[r] += __shfl_xor(s2r[r], off);
        }
    }
    if (lq == 0) {
        #pragma unroll
        for (int r = 0; r < 4; ++r) { sL[w][g][r] = sr[r]; s2L[w][g][r] = s2r[r]; }
    }
    __syncthreads();
    #pragma unroll
    for (int r = 0; r < 4; ++r) {
        float s = 0.f, s2 = 0.f;
        #pragma unroll
        for (int ww = 0; ww < 4; ++ww) { s += sL[ww][g][r]; s2 += s2L[ww][g][r]; }
        float mu = s * (1.f / CC);
        float var = s2 * (1.f / CC) - mu * mu;
        float rstd = rsqrtf(var + 1e-5f);
        size_t rowoff = (size_t)(row0 + g * 4 + r) * CC;
        #pragma unroll
        for (int ct = 0; ct < 2; ++ct) {
            float y = (v[ct][r] - mu) * rstd * gam[cols[ct]] + bet[cols[ct]];
            outf[rowoff + cols[ct]] = y;
            outb[rowoff + cols[ct]] = bf16rne(y);
        }
    }
}

// ---------------------------------------------------------------------------
// MFMA flash attention, fixed-shift softmax, sequence-aligned split-K with
// IN-BLOCK combine. Block = 1024 threads = 16 waves = 4 q-tiles x 4 z-splits.
// Wave (z, qt): z-group of 4 waves cooperatively stages its z-range K/V tiles
// (double-buffered LDS, 1 barrier/tile); partials reduced through LDS at the
// end; final bf16 attb written directly (no po/pl/combine kernel).
__global__ __launch_bounds__(1024, 8) void attn_mfma_kernel(
        const short* __restrict__ Qb, const short* __restrict__ Kh,
        const short* __restrict__ Vt, const float* __restrict__ kbw,
        short* __restrict__ attb) {
    __shared__ short Kl[4][2][32 * KROW];
    __shared__ short Vl[4][2][16 * VROW];
    __shared__ float oL[4][4][256];     // [qt][z][q*16+d]
    __shared__ float psL[4][4][16];     // [qt][z][q]

    const int tid  = threadIdx.x;
    const int lane = tid & 63;
    const int w    = tid >> 6;          // 0..15
    const int z    = w >> 2;            // sequence split
    const int qt   = w & 3;             // q-tile slot in block
    const int lq = lane & 15;
    const int g  = lane >> 4;
    const int h  = blockIdx.y;
    const int qtile = blockIdx.x * 4 + qt;
    const bool qv = qtile < LL / 16;
    const int q0 = qtile * 16;
    const int hd0 = h * 16;
    const int kbase = z * NN;

    bf16x4 qf = {0, 0, 0, 0};
    if (qv) qf = *(const bf16x4*)(Qb + (size_t)(q0 + lq) * CC + hd0 + 4 * g);

    // ones-row A fragment: A[0][k] = 1 -> D[0][q] = sum_k P[k][q]
    const short onev = (lq == 0) ? (short)0x3F80 : (short)0;
    const bf16x4 af1 = {onev, onev, onev, onev};

    // staging: z-group = threads [z*256, z*256+255]; zt = index within group
    const int zt = tid & 255;
    const short* kgp = Kh + ((size_t)h * LL + kbase) * 16 + zt * 2;
    const short* vgp = Vt + (size_t)(hd0 + (zt >> 4)) * LL + kbase + (zt & 15) * 2;
    short* kwp = &Kl[z][0][0] + (zt >> 3) * KROW + (zt & 7) * 2;
    short* vwp = &Vl[z][0][0] + (zt >> 4) * VROW + (zt & 15) * 2;

    f32x4 o  = {0.f, 0.f, 0.f, 0.f};
    f32x4 ps = {0.f, 0.f, 0.f, 0.f};

    {   // prologue: stage tile 0 into buf 0
        unsigned kd = *(const unsigned*)kgp;
        unsigned vd = *(const unsigned*)vgp;
        *(unsigned*)kwp = kd;
        *(unsigned*)vwp = vd;
    }
    __syncthreads();

    for (int t = 0; t < 32; ++t) {
        unsigned kd, vd;
        if (t < 31) {   // issue next tile's loads early (T14)
            kd = *(const unsigned*)(kgp + (size_t)(t + 1) * 32 * 16);
            vd = *(const unsigned*)(vgp + (t + 1) * 32);
        }
        const short* kb = &Kl[z][t & 1][0];
        const short* vb = &Vl[z][t & 1][0];
        if (t < 31) {
            bf16x4 K0 = *(const bf16x4*)(kb + lq * KROW + 4 * g);
            bf16x4 K1 = *(const bf16x4*)(kb + (16 + lq) * KROW + 4 * g);
            bf16x4 V0 = *(const bf16x4*)(vb + lq * VROW + 4 * g);
            bf16x4 V1 = *(const bf16x4*)(vb + lq * VROW + 16 + 4 * g);
            const f32x4 zz = {0.f, 0.f, 0.f, 0.f};
            f32x4 s0 = __builtin_amdgcn_mfma_f32_16x16x16bf16_1k(K0, qf, zz, 0, 0, 0);
            f32x4 s1 = __builtin_amdgcn_mfma_f32_16x16x16bf16_1k(K1, qf, zz, 0, 0, 0);
            float p0[4], p1[4];
            #pragma unroll
            for (int r = 0; r < 4; ++r) {
                p0[r] = __builtin_amdgcn_exp2f(s0[r]);
                p1[r] = __builtin_amdgcn_exp2f(s1[r]);
            }
            bf16x4 pt0 = pack4(p0);
            bf16x4 pt1 = pack4(p1);
            o  = __builtin_amdgcn_mfma_f32_16x16x16bf16_1k(V0, pt0, o, 0, 0, 0);
            o  = __builtin_amdgcn_mfma_f32_16x16x16bf16_1k(V1, pt1, o, 0, 0, 0);
            ps = __builtin_amdgcn_mfma_f32_16x16x16bf16_1k(af1, pt0, ps, 0, 0, 0);
            ps = __builtin_amdgcn_mfma_f32_16x16x16bf16_1k(af1, pt1, ps, 0, 0, 0);
            // write next tile into the other buffer, then barrier
            *(unsigned*)(kwp + ((t + 1) & 1) * 32 * KROW) = kd;
            *(unsigned*)(vwp + ((t + 1) & 1) * 16 * VROW) = vd;
            __syncthreads();
        } else {
            // tail: local keys 992..999 valid; mask P (g>=2) AND V-frag
            bf16x4 K0 = *(const bf16x4*)(kb + lq * KROW + 4 * g);
            bf16x4 V0 = *(const bf16x4*)(vb + lq * VROW + 4 * g);
            if (g >= 2) V0 = (bf16x4){0, 0, 0, 0};
            const f32x4 zz = {0.f, 0.f, 0.f, 0.f};
            f32x4 s0 = __builtin_amdgcn_mfma_f32_16x16x16bf16_1k(K0, qf, zz, 0, 0, 0);
            float p0[4];
            #pragma unroll
            for (int r = 0; r < 4; ++r)
                p0[r] = (g < 2) ? __builtin_amdgcn_exp2f(s0[r]) : 0.f;
            bf16x4 pt0 = pack4(p0);
            o  = __builtin_amdgcn_mfma_f32_16x16x16bf16_1k(V0, pt0, o, 0, 0, 0);
            ps = __builtin_amdgcn_mfma_f32_16x16x16bf16_1k(af1, pt0, ps, 0, 0, 0);
        }
    }

    // in-block split-K combine: partials -> LDS -> z==0 waves reduce & write
    *(f32x4*)&oL[qt][z][lq * 16 + 4 * g] = o;
    if (g == 0) psL[qt][z][lq] = ps[0];
    __syncthreads();

    if (z == 0 && qv) {
        const f32x4 kv = *(const f32x4*)kbw;   // wz for z=0..3
        const int q  = lane >> 2;
        const int d4 = (lane & 3) * 4;
        f32x4 acc = {0.f, 0.f, 0.f, 0.f};
        float den = 0.f;
        #pragma unroll
        for (int zz = 0; zz < 4; ++zz) {
            f32x4 tz = *(const f32x4*)&oL[qt][zz][q * 16 + d4];
            float wz = kv[zz];
            acc[0] += tz[0] * wz; acc[1] += tz[1] * wz;
            acc[2] += tz[2] * wz; acc[3] += tz[3] * wz;
            den += wz * psL[qt][zz][q];
        }
        float inv = 1.f / den;
        bf16x4 res = {bf16rne(acc[0] * inv), bf16rne(acc[1] * inv),
                      bf16rne(acc[2] * inv), bf16rne(acc[3] * inv)};
        *(bf16x4*)(attb + (size_t)(q0 + q) * CC + hd0 + d4) = res;
    }
}

// ---------------------------------------------------------------------------
extern "C" void kernel_launch(void* const* d_in, const int* in_sizes, int n_in,
                              void* d_out, int out_size, void* d_ws, size_t ws_size,
                              hipStream_t stream) {
    const float* z    = (const float*)d_in[0];
    const float* r    = (const float*)d_in[1];
    const float* se   = (const float*)d_in[2];
    const float* Wq   = (const float*)d_in[3];
    const float* Wk   = (const float*)d_in[4];
    const float* Wv   = (const float*)d_in[5];
    const float* Wp   = (const float*)d_in[6];
    const float* beta = (const float*)d_in[7];
    const float* ln1g = (const float*)d_in[8];
    const float* ln1b = (const float*)d_in[9];
    const float* w1   = (const float*)d_in[10];
    const float* b1   = (const float*)d_in[11];
    const float* w2   = (const float*)d_in[12];
    const float* b2   = (const float*)d_in[13];
    const float* ln2g = (const float*)d_in[14];
    const float* ln2b = (const float*)d_in[15];
    float* out = (float*)d_out;

    float* ws   = (float*)d_ws;
    float* tok  = ws;                        // 512000 f
    float* kbw  = tok + LL * CC;             // 8 f (16B-aligned)
    short* tokb = (short*)(kbw + 8);         // 512000 sh
    short* attb = tokb + LL * CC;
    short* Qb   = attb + LL * CC;
    short* Kh   = Qb   + LL * CC;            // head-major [H][L][16]
    short* Vt   = Kh   + LL * CC;            // transposed [C][L]
    short* hdn  = Vt   + LL * CC;            // 2,048,000 sh (FFN phase)
    short* wt8  = hdn  + LL * 4 * CC;
    short* w1t  = wt8  + 8 * 16384;
    short* w2t  = w1t  + 65536;

    prep_weights<<<1024, 256, 0, stream>>>(Wq, Wk, Wv, Wp, w1, w2, wt8, w1t, w2t);
    tokenize_kernel<<<2000, 256, 0, stream>>>(z, se, tok, tokb);
    kbw_kernel<<<1, 64, 0, stream>>>(r, beta, kbw);

    for (int l = 0; l < NLAYER; ++l) {
        const short* wqt = wt8 + (size_t)(0 * 2 + l) * 16384;
        const short* wkt = wt8 + (size_t)(1 * 2 + l) * 16384;
        const short* wvt = wt8 + (size_t)(2 * 2 + l) * 16384;
        const short* wpt = wt8 + (size_t)(3 * 2 + l) * 16384;
        mfma_gemm3<<<dim3(LL / 16, 1, 3), 256, 0, stream>>>(
            tokb, wqt, wkt, wvt, Qb, Kh, Vt, LL, CC, CC);
        attn_mfma_kernel<<<dim3((LL / 16 + 3) / 4, 8), 1024, 0, stream>>>(
            Qb, Kh, Vt, kbw + l * KSPLIT, attb);
        mfma_gemm_ln<<<LL / 16, 256, 0, stream>>>(
            attb, wpt, nullptr, tok, ln1g + l * CC, ln1b + l * CC,
            tok, tokb, LL, CC);
    }

    mfma_gemm<<<dim3(LL / 16, 4), 256, 0, stream>>>(tokb, w1t, b1, hdn, LL, CC, 4 * CC, 1 | 2);
    mfma_gemm_ln<<<LL / 16, 256, 0, stream>>>(
        hdn, w2t, b2, tok, ln2g, ln2b, tok, tokb, LL, 4 * CC);

    detok_kernel<<<2000, 256, 0, stream>>>(tok, out);
}